// Round 2
// baseline (499.839 us; speedup 1.0000x reference)
//
#include <hip/hip_runtime.h>
#include <hip/hip_bf16.h>

// Problem constants (fixed by the reference)
#define Hd   1024
#define Bd   32
#define Nd   20
#define Kd   10
#define NKd  200   // N*K support rows per batch
#define NKP  208   // padded to 13 * 16
#define Qd   2048
#define BM   128   // query rows per block (4 waves x 32 rows each)
#define ZR   64    // z-buffer rows per epilogue pass (two passes)
#define ZLD  209   // z-buffer LDS row stride
#define EPSf 1e-5f
#define TAU  0.02f // top-2 gap below which we refine in fp64
#define MAXF 2048
#define TCH  (832 * 8)   // ushorts per (batch,tile,plane) block
#define PLB  (TCH * 2)   // plane stride in bytes  (13312)
#define BUFB (2 * PLB)   // buffer stride in bytes (26624)

typedef __attribute__((ext_vector_type(8))) short bf16x8;
typedef __attribute__((ext_vector_type(4))) float f32x4;
typedef __attribute__((ext_vector_type(4))) unsigned int u32x4;

// chunk swizzle: slot = k8 ^ SWS(row). SWS(r) changes under r->r+4/+8/+12, so
// every consecutive-8-lane phase of a ds_read_b128 hits 8 distinct 16B slots.
#define SWS(r) (((r) ^ ((r) >> 2)) & 3)

static __device__ __forceinline__ unsigned short f2bf(float f) {
  union { float f; unsigned u; } c; c.f = f;
  unsigned r = c.u + 0x7FFFu + ((c.u >> 16) & 1u);  // RNE
  return (unsigned short)(r >> 16);
}
static __device__ __forceinline__ float bf2f(unsigned short h) {
  union { unsigned u; float f; } c; c.u = ((unsigned)h) << 16;
  return c.f;
}
static __device__ __forceinline__ float ubitf(unsigned u) {
  union { unsigned u; float f; } c; c.u = u; return c.f;
}
static __device__ __forceinline__ unsigned cvtpk_bf16(float a, float b) {
  unsigned r;  // dst.lo16 = bf16(a), dst.hi16 = bf16(b)
  asm("v_cvt_pk_bf16_f32 %0, %1, %2" : "=v"(r) : "v"(a), "v"(b));
  return r;
}
static __device__ __forceinline__ void gload_lds16(const void* g, void* l) {
  __builtin_amdgcn_global_load_lds(
      (const __attribute__((address_space(1))) unsigned int*)g,
      (__attribute__((address_space(3))) unsigned int*)l, 16, 0, 0);
}

// ---- LayerNorm support -> split bf16 (hi, lo) planes in tile-major, pre-swizzled
//      layout: plane[((b*32 + T)*832 + row*4 + (k8 ^ SWS(row))) * 8 ..+8].
//      Also per-row scalars G = sum(gamma*sn), Bt = sum(beta*sn). One wave/row.
__global__ __launch_bounds__(256) void ln_support(const float* __restrict__ x,
                                                  const float* __restrict__ gamma,
                                                  const float* __restrict__ beta,
                                                  unsigned short* __restrict__ y_hi,
                                                  unsigned short* __restrict__ y_lo,
                                                  float* __restrict__ Gv,
                                                  float* __restrict__ Bv) {
  int wave = threadIdx.x >> 6, lane = threadIdx.x & 63;
  int p = blockIdx.x * 4 + wave;          // padded row id in [0, Bd*NKP)
  int b = p / NKP, rr = p - b * NKP;
  int T0 = lane >> 1;                     // this lane's K-tile (2 lanes per tile)
  int k8base = (lane & 1) * 2;            // first of this lane's 2 chunks in the tile
  int sw = SWS(rr);
  size_t chunkbase = (size_t)b * 32 * TCH + (size_t)T0 * TCH + (size_t)rr * 32;

  if (rr >= NKd) {                        // padding row: zero-fill
    bf16x8 z8 = {0, 0, 0, 0, 0, 0, 0, 0};
#pragma unroll
    for (int pr = 0; pr < 2; ++pr) {
      size_t off = chunkbase + (size_t)(((k8base + pr) ^ sw) * 8);
      *(bf16x8*)(y_hi + off) = z8;
      *(bf16x8*)(y_lo + off) = z8;
    }
    if (lane == 0) { Gv[p] = 0.f; Bv[p] = 0.f; }
    return;
  }
  // lane handles cols [lane*16, lane*16+16)
  const float4* xr = (const float4*)(x + ((size_t)b * NKd + rr) * Hd);
  const float4* gr = (const float4*)gamma;
  const float4* br = (const float4*)beta;
  float4 v[4];
  float s = 0.f, ss = 0.f;
#pragma unroll
  for (int j = 0; j < 4; ++j) {
    v[j] = xr[lane * 4 + j];
    s  += v[j].x + v[j].y + v[j].z + v[j].w;
    ss += v[j].x * v[j].x + v[j].y * v[j].y + v[j].z * v[j].z + v[j].w * v[j].w;
  }
#pragma unroll
  for (int o = 32; o; o >>= 1) { s += __shfl_xor(s, o, 64); ss += __shfl_xor(ss, o, 64); }
  float mean = s * (1.0f / Hd);
  float rstd = rsqrtf(ss * (1.0f / Hd) - mean * mean + EPSf);

  float nx[16];
  float sg = 0.f, sb = 0.f;
#pragma unroll
  for (int j = 0; j < 4; ++j) {
    float4 g = gr[lane * 4 + j], bb = br[lane * 4 + j];
    float xv[4] = {v[j].x, v[j].y, v[j].z, v[j].w};
    float gv4[4] = {g.x, g.y, g.z, g.w};
    float bv4[4] = {bb.x, bb.y, bb.z, bb.w};
#pragma unroll
    for (int e = 0; e < 4; ++e) {
      float n = (xv[e] - mean) * rstd * gv4[e] + bv4[e];
      nx[j * 4 + e] = n;
      sg += n * gv4[e];
      sb += n * bv4[e];
    }
  }
#pragma unroll
  for (int pr = 0; pr < 2; ++pr) {
    bf16x8 ph, pl;
#pragma unroll
    for (int e = 0; e < 8; ++e) {
      float n = nx[pr * 8 + e];
      unsigned short h = f2bf(n);
      ph[e] = (short)h;
      pl[e] = (short)f2bf(n - bf2f(h));
    }
    size_t off = chunkbase + (size_t)(((k8base + pr) ^ sw) * 8);
    *(bf16x8*)(y_hi + off) = ph;
    *(bf16x8*)(y_lo + off) = pl;
  }
#pragma unroll
  for (int o = 32; o; o >>= 1) { sg += __shfl_xor(sg, o, 64); sb += __shfl_xor(sb, o, 64); }
  if (lane == 0) { Gv[p] = sg; Bv[p] = sb; }
}

// split x*gamma into bf16 hi/lo planes (packed via v_cvt_pk_bf16_f32) and
// accumulate raw-x stats. hi rounding mode is irrelevant (lo catches residual).
static __device__ __forceinline__ void split8(float4 xa, float4 xb, float4 ga, float4 gb,
                                              float& sx, float& sxx,
                                              bf16x8& AH, bf16x8& AL) {
  float x[8] = {xa.x, xa.y, xa.z, xa.w, xb.x, xb.y, xb.z, xb.w};
  float g[8] = {ga.x, ga.y, ga.z, ga.w, gb.x, gb.y, gb.z, gb.w};
  float u[8];
#pragma unroll
  for (int e = 0; e < 8; ++e) {
    sx += x[e];
    sxx = fmaf(x[e], x[e], sxx);
    u[e] = x[e] * g[e];
  }
  unsigned h[4], l[4];
#pragma unroll
  for (int p = 0; p < 4; ++p) {
    h[p] = cvtpk_bf16(u[2 * p], u[2 * p + 1]);
    float r0 = ubitf(h[p] << 16);
    float r1 = ubitf(h[p] & 0xFFFF0000u);
    l[p] = cvtpk_bf16(u[2 * p] - r0, u[2 * p + 1] - r1);
  }
  AH = __builtin_bit_cast(bf16x8, (u32x4){h[0], h[1], h[2], h[3]});
  AL = __builtin_bit_cast(bf16x8, (u32x4){l[0], l[1], l[2], l[3]});
}

// ---- fused GEMM + stats + group-max/min/argmax.
// Each wave owns M=32 query rows (2 A-fragments). B triple-buffered via
// global_load_lds with a 2-tile-deep pipeline: raw s_barrier + counted
// s_waitcnt vmcnt(N) (T4) -- DMA stays in flight across barriers, never
// drained to 0 in the main loop. setprio(1) around the MFMA cluster (T5).
// Per-wave VMEM issue order per iteration T (pinned by fences):
//   [split A(T)] [loadA(T+1): 6 loads] [DMA(T+2): 7 loads]
// => top-of-iter wait for DMA(T) done = vmcnt(6 + 7) = 13.
// z[q][s] = rstd_q * D - mean_q * rstd_q * G[s] + Bt[s],  D = (x .* gamma) . sn
__global__ __launch_bounds__(256, 2) void gemm_reduce(
    const float* __restrict__ query,
    const unsigned short* __restrict__ s_hi, const unsigned short* __restrict__ s_lo,
    const float* __restrict__ gamma,
    const float* __restrict__ Gv, const float* __restrict__ Bv,
    float* __restrict__ out_logits, float* __restrict__ out_pred,
    int* __restrict__ flag_cnt, int* __restrict__ flag_list) {
  __shared__ __align__(16) union {
    unsigned short B[3][2][TCH];   // [buf][plane]: 79872 B
    float z[ZR][ZLD];              // 53504 B (one 64-row pass at a time)
  } sm;
  __shared__ __align__(16) char dma_pad[1024];  // dump for waves 2/3's padded DMA

  // XCD-locality decode: all 16 m-tiles of a batch land on one XCD (lin % 8)
  int lin = blockIdx.x;
  int xcd = lin & 7, sl = lin >> 3;
  int b = xcd + 8 * (sl >> 4);
  int m0 = (sl & 15) * BM;
  int t = threadIdx.x;
  int wave = t >> 6, lane = t & 63;
  int m = lane & 15, quad = lane >> 4;

  const size_t qrow0 = (size_t)b * Qd + m0;
  const float* qf0 = query + (qrow0 + wave * 32 + m) * Hd;   // fragment 0 row
  const float* qf1 = qf0 + 16 * Hd;                          // fragment 1 row
  const unsigned short* hb = s_hi + (size_t)b * 32 * TCH;
  const unsigned short* lb = s_lo + (size_t)b * 32 * TCH;

  char* ldsB = (char*)&sm.B[0][0][0];
  // read slot depends only on m (row = nt*16+m) -> one base VGPR per buffer.
  const char* rdB = ldsB + m * 64 + ((quad ^ SWS(m)) * 16);

  // 7 DMA instrs per wave per tile (26 real + 2 padded into dma_pad) so the
  // in-flight count is wave-uniform.
  auto issue_dma = [&](int Tn, int bufsel) {
    size_t toff = (size_t)Tn * TCH;
    char* dstb = ldsB + bufsel * BUFB;
#pragma unroll
    for (int i = 0; i < 7; ++i) {
      int j = wave + i * 4;
      bool real = (j < 26);
      int pl = (real && j >= 13) ? 1 : 0;
      int jj = real ? (j - pl * 13) : 0;
      const unsigned short* src = (pl ? lb : hb) + toff + (size_t)jj * 512 + lane * 8;
      void* dst = real ? (void*)(dstb + pl * PLB + jj * 1024) : (void*)dma_pad;
      gload_lds16(src, dst);
    }
  };

  float4 xq00, xq01, xq10, xq11, gq0, gq1;
  auto loadA = [&](int T) {
    int ko = T * 32 + quad * 8;
    const float4* g4 = (const float4*)(gamma + ko);
    gq0 = g4[0]; gq1 = g4[1];
    const float4* q0 = (const float4*)(qf0 + ko);
    xq00 = q0[0]; xq01 = q0[1];
    const float4* q1 = (const float4*)(qf1 + ko);
    xq10 = q1[0]; xq11 = q1[1];
  };

  f32x4 acc0[13], acc1[13];
#pragma unroll
  for (int i = 0; i < 13; ++i) {
    acc0[i] = (f32x4){0.f, 0.f, 0.f, 0.f};
    acc1[i] = (f32x4){0.f, 0.f, 0.f, 0.f};
  }
  float sx0 = 0.f, sxx0 = 0.f, sx1 = 0.f, sxx1 = 0.f;

  // prologue: DMA(0), then A(0), then DMA(1) -- order pinned so the counted
  // waits (in-order vmcnt retirement) never force a drain of younger DMA.
  issue_dma(0, 0);
  __builtin_amdgcn_sched_barrier(0);
  asm volatile("" ::: "memory");
  loadA(0);
  __builtin_amdgcn_sched_barrier(0);
  asm volatile("" ::: "memory");
  issue_dma(1, 1);

  int bu = 0;  // buffer holding tile T
  for (int T = 0; T < 32; ++T) {
    // wait: own DMA(T) complete. Outstanding allowed: A(T)[6] + DMA(T+1)[7].
    if (T < 31) asm volatile("s_waitcnt vmcnt(13)" ::: "memory");
    else        asm volatile("s_waitcnt vmcnt(6)" ::: "memory");
    __builtin_amdgcn_s_barrier();    // all waves' DMA(T) landed; buf(T) ready
    __builtin_amdgcn_sched_barrier(0);

    // A-path: consume A(T) (compiler waits vmcnt(7), keeping DMA(T+1) live)
    bf16x8 ah0, al0, ah1, al1;
    split8(xq00, xq01, gq0, gq1, sx0, sxx0, ah0, al0);
    split8(xq10, xq11, gq0, gq1, sx1, sxx1, ah1, al1);
    if (T + 1 < 32) loadA(T + 1);
    __builtin_amdgcn_sched_barrier(0);
    asm volatile("" ::: "memory");   // pin: A(T+1) loads precede DMA(T+2)
    if (T + 2 < 32) {
      int bd = bu + 2; if (bd >= 3) bd -= 3;
      issue_dma(T + 2, bd);          // in flight across the next two barriers
    }

    const char* Bu = rdB + bu * BUFB;
    __builtin_amdgcn_s_setprio(1);
#pragma unroll
    for (int nt = 0; nt < 13; ++nt) {
      bf16x8 bh = *(const bf16x8*)(Bu + nt * 1024);
      bf16x8 bl = *(const bf16x8*)(Bu + PLB + nt * 1024);
      acc0[nt] = __builtin_amdgcn_mfma_f32_16x16x32_bf16(ah0, bh, acc0[nt], 0, 0, 0);
      acc1[nt] = __builtin_amdgcn_mfma_f32_16x16x32_bf16(ah1, bh, acc1[nt], 0, 0, 0);
      acc0[nt] = __builtin_amdgcn_mfma_f32_16x16x32_bf16(al0, bh, acc0[nt], 0, 0, 0);
      acc1[nt] = __builtin_amdgcn_mfma_f32_16x16x32_bf16(al1, bh, acc1[nt], 0, 0, 0);
      acc0[nt] = __builtin_amdgcn_mfma_f32_16x16x32_bf16(ah0, bl, acc0[nt], 0, 0, 0);
      acc1[nt] = __builtin_amdgcn_mfma_f32_16x16x32_bf16(ah1, bl, acc1[nt], 0, 0, 0);
    }
    __builtin_amdgcn_s_setprio(0);
    if (++bu == 3) bu = 0;
  }

  // row stats: butterfly over quads -> every lane holds totals for its m
  sx0 += __shfl_xor(sx0, 16, 64);  sxx0 += __shfl_xor(sxx0, 16, 64);
  sx0 += __shfl_xor(sx0, 32, 64);  sxx0 += __shfl_xor(sxx0, 32, 64);
  sx1 += __shfl_xor(sx1, 16, 64);  sxx1 += __shfl_xor(sxx1, 16, 64);
  sx1 += __shfl_xor(sx1, 32, 64);  sxx1 += __shfl_xor(sxx1, 32, 64);
  float mean0 = sx0 * (1.0f / Hd);
  float rstd0 = rsqrtf(sxx0 * (1.0f / Hd) - mean0 * mean0 + EPSf);
  float mean1 = sx1 * (1.0f / Hd);
  float rstd1 = rsqrtf(sxx1 * (1.0f / Hd) - mean1 * mean1 + EPSf);

  float Gc[13], Bc[13];
#pragma unroll
  for (int nt = 0; nt < 13; ++nt) {
    int col = b * NKP + nt * 16 + m;
    Gc[nt] = Gv[col];
    Bc[nt] = Bv[col];
  }

  // epilogue in 2 passes of 64 rows (z-buffer aliases the dead B buffers)
  // C layout: col = lane&15, row = quad*4 + reg
#pragma unroll
  for (int pass = 0; pass < 2; ++pass) {
    __syncthreads();  // B (or previous z pass) fully consumed
    if ((wave >> 1) == pass) {
      int zb = (wave & 1) * 32;
#pragma unroll
      for (int r = 0; r < 4; ++r) {
        int lr = quad * 4 + r;
        {
          float mn = __shfl(mean0, lr, 16), rs = __shfl(rstd0, lr, 16);
          float mrs = mn * rs;
#pragma unroll
          for (int nt = 0; nt < 13; ++nt)
            sm.z[zb + lr][nt * 16 + m] = rs * acc0[nt][r] - mrs * Gc[nt] + Bc[nt];
        }
        {
          float mn = __shfl(mean1, lr, 16), rs = __shfl(rstd1, lr, 16);
          float mrs = mn * rs;
#pragma unroll
          for (int nt = 0; nt < 13; ++nt)
            sm.z[zb + 16 + lr][nt * 16 + m] = rs * acc1[nt][r] - mrs * Gc[nt] + Bc[nt];
        }
      }
    }
    __syncthreads();

    // phase 1: group maxes in-place (64 rows x 20 groups of 10)
    for (int i = t; i < ZR * Nd; i += 256) {
      int row = i / Nd, g = i - row * Nd;
      float* zp = &sm.z[row][g * Kd];
      float mx = zp[0];
#pragma unroll
      for (int j = 1; j < Kd; ++j) mx = fmaxf(mx, zp[j]);
      zp[0] = mx;
    }
    __syncthreads();

    // phase 2: min over N, concat, argmax (+top-2 gap flag), write
    if (t < ZR) {
      int row = t;
      float mn = 3.4e38f, v1 = -3.4e38f, v2 = -3.4e38f;
      int best = 0;
      size_t orow = qrow0 + pass * ZR + row;
      float* lp = out_logits + orow * (Nd + 1);
#pragma unroll
      for (int n = 0; n < Nd; ++n) {
        float v = sm.z[row][n * Kd];
        lp[n] = v;
        mn = fminf(mn, v);
        if (v > v1) { v2 = v1; v1 = v; best = n; }  // first-occurrence argmax
        else v2 = fmaxf(v2, v);
      }
      lp[Nd] = mn - 1.0f;  // strictly below min, never the argmax
      out_pred[orow] = (float)best;
      if (v1 - v2 < TAU) {
        int idx = atomicAdd(flag_cnt, 1);
        if (idx < MAXF) flag_list[idx] = (int)orow;
      }
    }
  }
}

// ---------------- fp64 exact refinement for near-tie rows ----------------
__global__ __launch_bounds__(256) void refine_pred(
    const float* __restrict__ query, const float* __restrict__ support,
    const float* __restrict__ gamma, const float* __restrict__ beta,
    const int* __restrict__ flag_cnt, const int* __restrict__ flag_list,
    float* __restrict__ out_pred) {
  __shared__ double A[Hd];     // qn_full * gamma
  __shared__ double red[16];
  __shared__ double zbuf[NKd];
  __shared__ double gmax[Nd];
  int cnt = *flag_cnt; if (cnt > MAXF) cnt = MAXF;
  if ((int)blockIdx.x >= cnt) return;
  int qrow = flag_list[blockIdx.x];
  int b = qrow / Qd;
  int t = threadIdx.x, lane = t & 63, w = t >> 6;
  const float* qx = query + (size_t)qrow * Hd;
  float xv[4];
  double sx = 0.0, sxx = 0.0;
#pragma unroll
  for (int i = 0; i < 4; ++i) {
    xv[i] = qx[t * 4 + i];
    sx += (double)xv[i]; sxx += (double)xv[i] * (double)xv[i];
  }
#pragma unroll
  for (int o = 32; o; o >>= 1) { sx += __shfl_xor(sx, o, 64); sxx += __shfl_xor(sxx, o, 64); }
  if (lane == 0) { red[w] = sx; red[8 + w] = sxx; }
  __syncthreads();
  double m = (red[0] + red[1] + red[2] + red[3]) * (1.0 / Hd);
  double var = (red[8] + red[9] + red[10] + red[11]) * (1.0 / Hd) - m * m;
  double r = 1.0 / sqrt(var + 1e-5);
  double s1 = 0.0, s2 = 0.0;
#pragma unroll
  for (int i = 0; i < 4; ++i) {
    int j = t * 4 + i;
    double g = (double)gamma[j], be = (double)beta[j];
    double qn = ((double)xv[i] - m) * r * g + be;
    double a = qn * g;
    A[j] = a; s1 += a; s2 += qn * be;
  }
#pragma unroll
  for (int o = 32; o; o >>= 1) { s1 += __shfl_xor(s1, o, 64); s2 += __shfl_xor(s2, o, 64); }
  __syncthreads();
  if (lane == 0) { red[w] = s1; red[8 + w] = s2; }
  __syncthreads();
  double S1 = red[0] + red[1] + red[2] + red[3];
  double S2 = red[8] + red[9] + red[10] + red[11];
  const float* sbase = support + (size_t)b * NKd * Hd;
  for (int row = w; row < NKd; row += 4) {
    const float* xr = sbase + (size_t)row * Hd;
    double tx = 0.0, txx = 0.0, tax = 0.0;
#pragma unroll
    for (int i = 0; i < 16; ++i) {
      int j = lane + i * 64;
      double x = (double)xr[j];
      tx += x; txx += x * x; tax += A[j] * x;
    }
#pragma unroll
    for (int o = 32; o; o >>= 1) {
      tx += __shfl_xor(tx, o, 64); txx += __shfl_xor(txx, o, 64); tax += __shfl_xor(tax, o, 64);
    }
    if (lane == 0) {
      double mm = tx * (1.0 / Hd);
      double vv = txx * (1.0 / Hd) - mm * mm;
      double rr = 1.0 / sqrt(vv + 1e-5);
      zbuf[row] = rr * (tax - mm * S1) + S2;
    }
  }
  __syncthreads();
  if (t < Nd) {
    double mx = zbuf[t * Kd];
#pragma unroll
    for (int j = 1; j < Kd; ++j) mx = fmax(mx, zbuf[t * Kd + j]);
    gmax[t] = mx;
  }
  __syncthreads();
  if (t == 0) {
    double bv = gmax[0]; int best = 0;
#pragma unroll
    for (int n = 1; n < Nd; ++n) if (gmax[n] > bv) { bv = gmax[n]; best = n; }
    out_pred[qrow] = (float)best;
  }
}

extern "C" void kernel_launch(void* const* d_in, const int* in_sizes, int n_in,
                              void* d_out, int out_size, void* d_ws, size_t ws_size,
                              hipStream_t stream) {
  const float* support = (const float*)d_in[0];
  const float* query   = (const float*)d_in[1];
  const float* gamma   = (const float*)d_in[2];
  const float* beta    = (const float*)d_in[3];

  float* out = (float*)d_out;
  float* out_logits = out;                                  // 32*2048*21
  float* out_pred   = out + (size_t)Bd * Qd * (Nd + 1);     // 32*2048

  const size_t plane = (size_t)Bd * 32 * TCH;               // == Bd*NKP*Hd elems
  unsigned short* s_hi = (unsigned short*)d_ws;             // 13.6 MB
  unsigned short* s_lo = s_hi + plane;                      // 13.6 MB
  char* p = (char*)(s_lo + plane);
  float* Gv = (float*)p;            p += (size_t)Bd * NKP * sizeof(float);
  float* Bv = (float*)p;            p += (size_t)Bd * NKP * sizeof(float);
  int* flag_cnt = (int*)p;
  int* flag_list = (int*)(p + 256);

  hipMemsetAsync(flag_cnt, 0, sizeof(int), stream);
  ln_support<<<(Bd * NKP) / 4, 256, 0, stream>>>(support, gamma, beta, s_hi, s_lo, Gv, Bv);
  gemm_reduce<<<Qd / BM * Bd, 256, 0, stream>>>(query, s_hi, s_lo, gamma, Gv, Bv,
                                                out_logits, out_pred, flag_cnt, flag_list);
  refine_pred<<<MAXF, 256, 0, stream>>>(query, support, gamma, beta, flag_cnt, flag_list, out_pred);
}

// Round 3
// 490.794 us; speedup vs baseline: 1.0184x; 1.0184x over previous
//
#include <hip/hip_runtime.h>
#include <hip/hip_bf16.h>

// Problem constants (fixed by the reference)
#define Hd   1024
#define Bd   32
#define Nd   20
#define Kd   10
#define NKd  200   // N*K support rows per batch
#define NKP  208   // padded to 13 * 16
#define Qd   2048
#define BM   64    // query rows per block (4 waves x 16 rows) -> grid 1024 = 4 blocks/CU
#define ZR   32    // z-buffer rows per epilogue pass (two passes)
#define ZLD  209   // z-buffer LDS row stride
#define EPSf 1e-5f
#define TAU  0.02f // top-2 gap below which we refine in fp64
#define MAXF 2048
#define TCH  (832 * 8)   // ushorts per (batch,tile,plane) block
#define PLB  (TCH * 2)   // plane stride in bytes  (13312)

typedef __attribute__((ext_vector_type(8))) short bf16x8;
typedef __attribute__((ext_vector_type(4))) float f32x4;
typedef __attribute__((ext_vector_type(4))) unsigned int u32x4;

// chunk swizzle: slot = k8 ^ SWS(row). SWS(r) changes under r->r+4/+8/+12, so
// every consecutive-8-lane phase of a ds_read_b128 hits 8 distinct 16B slots.
#define SWS(r) (((r) ^ ((r) >> 2)) & 3)

static __device__ __forceinline__ unsigned short f2bf(float f) {
  union { float f; unsigned u; } c; c.f = f;
  unsigned r = c.u + 0x7FFFu + ((c.u >> 16) & 1u);  // RNE
  return (unsigned short)(r >> 16);
}
static __device__ __forceinline__ float bf2f(unsigned short h) {
  union { unsigned u; float f; } c; c.u = ((unsigned)h) << 16;
  return c.f;
}
static __device__ __forceinline__ float ubitf(unsigned u) {
  union { unsigned u; float f; } c; c.u = u; return c.f;
}
static __device__ __forceinline__ unsigned cvtpk_bf16(float a, float b) {
  unsigned r;  // dst.lo16 = bf16(a), dst.hi16 = bf16(b)
  asm("v_cvt_pk_bf16_f32 %0, %1, %2" : "=v"(r) : "v"(a), "v"(b));
  return r;
}
static __device__ __forceinline__ void gload_lds16(const void* g, void* l) {
  __builtin_amdgcn_global_load_lds(
      (const __attribute__((address_space(1))) unsigned int*)g,
      (__attribute__((address_space(3))) unsigned int*)l, 16, 0, 0);
}

// ---- LayerNorm support -> split bf16 (hi, lo) planes in tile-major, pre-swizzled
//      layout: plane[((b*32 + T)*832 + row*4 + (k8 ^ SWS(row))) * 8 ..+8].
//      Also per-row scalars G = sum(gamma*sn), Bt = sum(beta*sn). One wave/row.
__global__ __launch_bounds__(256) void ln_support(const float* __restrict__ x,
                                                  const float* __restrict__ gamma,
                                                  const float* __restrict__ beta,
                                                  unsigned short* __restrict__ y_hi,
                                                  unsigned short* __restrict__ y_lo,
                                                  float* __restrict__ Gv,
                                                  float* __restrict__ Bv) {
  int wave = threadIdx.x >> 6, lane = threadIdx.x & 63;
  int p = blockIdx.x * 4 + wave;          // padded row id in [0, Bd*NKP)
  int b = p / NKP, rr = p - b * NKP;
  int T0 = lane >> 1;                     // this lane's K-tile (2 lanes per tile)
  int k8base = (lane & 1) * 2;            // first of this lane's 2 chunks in the tile
  int sw = SWS(rr);
  size_t chunkbase = (size_t)b * 32 * TCH + (size_t)T0 * TCH + (size_t)rr * 32;

  if (rr >= NKd) {                        // padding row: zero-fill
    bf16x8 z8 = {0, 0, 0, 0, 0, 0, 0, 0};
#pragma unroll
    for (int pr = 0; pr < 2; ++pr) {
      size_t off = chunkbase + (size_t)(((k8base + pr) ^ sw) * 8);
      *(bf16x8*)(y_hi + off) = z8;
      *(bf16x8*)(y_lo + off) = z8;
    }
    if (lane == 0) { Gv[p] = 0.f; Bv[p] = 0.f; }
    return;
  }
  // lane handles cols [lane*16, lane*16+16)
  const float4* xr = (const float4*)(x + ((size_t)b * NKd + rr) * Hd);
  const float4* gr = (const float4*)gamma;
  const float4* br = (const float4*)beta;
  float4 v[4];
  float s = 0.f, ss = 0.f;
#pragma unroll
  for (int j = 0; j < 4; ++j) {
    v[j] = xr[lane * 4 + j];
    s  += v[j].x + v[j].y + v[j].z + v[j].w;
    ss += v[j].x * v[j].x + v[j].y * v[j].y + v[j].z * v[j].z + v[j].w * v[j].w;
  }
#pragma unroll
  for (int o = 32; o; o >>= 1) { s += __shfl_xor(s, o, 64); ss += __shfl_xor(ss, o, 64); }
  float mean = s * (1.0f / Hd);
  float rstd = rsqrtf(ss * (1.0f / Hd) - mean * mean + EPSf);

  float nx[16];
  float sg = 0.f, sb = 0.f;
#pragma unroll
  for (int j = 0; j < 4; ++j) {
    float4 g = gr[lane * 4 + j], bb = br[lane * 4 + j];
    float xv[4] = {v[j].x, v[j].y, v[j].z, v[j].w};
    float gv4[4] = {g.x, g.y, g.z, g.w};
    float bv4[4] = {bb.x, bb.y, bb.z, bb.w};
#pragma unroll
    for (int e = 0; e < 4; ++e) {
      float n = (xv[e] - mean) * rstd * gv4[e] + bv4[e];
      nx[j * 4 + e] = n;
      sg += n * gv4[e];
      sb += n * bv4[e];
    }
  }
#pragma unroll
  for (int pr = 0; pr < 2; ++pr) {
    bf16x8 ph, pl;
#pragma unroll
    for (int e = 0; e < 8; ++e) {
      float n = nx[pr * 8 + e];
      unsigned short h = f2bf(n);
      ph[e] = (short)h;
      pl[e] = (short)f2bf(n - bf2f(h));
    }
    size_t off = chunkbase + (size_t)(((k8base + pr) ^ sw) * 8);
    *(bf16x8*)(y_hi + off) = ph;
    *(bf16x8*)(y_lo + off) = pl;
  }
#pragma unroll
  for (int o = 32; o; o >>= 1) { sg += __shfl_xor(sg, o, 64); sb += __shfl_xor(sb, o, 64); }
  if (lane == 0) { Gv[p] = sg; Bv[p] = sb; }
}

// split x*gamma into bf16 hi/lo planes (packed via v_cvt_pk_bf16_f32) and
// accumulate raw-x stats. hi rounding mode is irrelevant (lo catches residual).
static __device__ __forceinline__ void split8(float4 xa, float4 xb, float4 ga, float4 gb,
                                              float& sx, float& sxx,
                                              bf16x8& AH, bf16x8& AL) {
  float x[8] = {xa.x, xa.y, xa.z, xa.w, xb.x, xb.y, xb.z, xb.w};
  float g[8] = {ga.x, ga.y, ga.z, ga.w, gb.x, gb.y, gb.z, gb.w};
  float u[8];
#pragma unroll
  for (int e = 0; e < 8; ++e) {
    sx += x[e];
    sxx = fmaf(x[e], x[e], sxx);
    u[e] = x[e] * g[e];
  }
  unsigned h[4], l[4];
#pragma unroll
  for (int p = 0; p < 4; ++p) {
    h[p] = cvtpk_bf16(u[2 * p], u[2 * p + 1]);
    float r0 = ubitf(h[p] << 16);
    float r1 = ubitf(h[p] & 0xFFFF0000u);
    l[p] = cvtpk_bf16(u[2 * p] - r0, u[2 * p + 1] - r1);
  }
  AH = __builtin_bit_cast(bf16x8, (u32x4){h[0], h[1], h[2], h[3]});
  AL = __builtin_bit_cast(bf16x8, (u32x4){l[0], l[1], l[2], l[3]});
}

// ---- fused GEMM + stats + group-max/min/argmax.
// High-occupancy variant: BM=64 -> grid 1024 = exactly 4 blocks/CU (16 waves/CU).
// Single B buffer (26.6 KB LDS) + plain __syncthreads: per-T DMA drain is
// exposed within a block but hidden by the other 3 resident blocks' MFMA
// phases (cross-block TLP, m114). Intra-block pipelining was measured neutral
// at 2 blocks/CU (R2), so occupancy is the binding constraint.
// z[q][s] = rstd_q * D - mean_q * rstd_q * G[s] + Bt[s],  D = (x .* gamma) . sn
__global__ __launch_bounds__(256, 4) void gemm_reduce(
    const float* __restrict__ query,
    const unsigned short* __restrict__ s_hi, const unsigned short* __restrict__ s_lo,
    const float* __restrict__ gamma,
    const float* __restrict__ Gv, const float* __restrict__ Bv,
    float* __restrict__ out_logits, float* __restrict__ out_pred,
    int* __restrict__ flag_cnt, int* __restrict__ flag_list) {
  __shared__ __align__(16) union {
    unsigned short Bb[2][TCH];   // [plane]: 26624 B
    float z[ZR][ZLD];            // 26752 B (one 32-row pass at a time)
  } sm;

  // XCD-locality decode: all 32 m-tiles of a batch land on one XCD (lin % 8)
  int lin = blockIdx.x;
  int xcd = lin & 7, sl = lin >> 3;
  int b = xcd + 8 * (sl >> 5);
  int m0 = (sl & 31) * BM;
  int t = threadIdx.x;
  int wave = t >> 6, lane = t & 63;
  int m = lane & 15, quad = lane >> 4;

  const size_t qrow0 = (size_t)b * Qd + m0;
  const float* qf0 = query + (qrow0 + wave * 16 + m) * Hd;
  const unsigned short* hb = s_hi + (size_t)b * 32 * TCH;
  const unsigned short* lb = s_lo + (size_t)b * 32 * TCH;

  char* ldsB = (char*)&sm.Bb[0][0];
  // read slot depends only on m (row = nt*16+m) -> one base VGPR; all 26
  // reads/T are base + compile-time offset.
  const char* rdB = ldsB + m * 64 + ((quad ^ SWS(m)) * 16);

  auto issue_dma = [&](int Tn) {
    size_t toff = (size_t)Tn * TCH;
    for (int j = wave; j < 26; j += 4) {
      int pl = j >= 13 ? 1 : 0, jj = j - pl * 13;
      const unsigned short* src = (pl ? lb : hb) + toff + (size_t)jj * 512 + lane * 8;
      gload_lds16(src, ldsB + pl * PLB + jj * 1024);
    }
  };

  float4 xq0, xq1, gq0, gq1;
  auto loadA = [&](int T) {
    int ko = T * 32 + quad * 8;
    const float4* g4 = (const float4*)(gamma + ko);
    gq0 = g4[0]; gq1 = g4[1];
    const float4* q0 = (const float4*)(qf0 + ko);
    xq0 = q0[0]; xq1 = q0[1];
  };

  f32x4 acc[13];
#pragma unroll
  for (int i = 0; i < 13; ++i) acc[i] = (f32x4){0.f, 0.f, 0.f, 0.f};
  float sx = 0.f, sxx = 0.f;

  // prologue: DMA tile 0; prefetch A(0) into registers
  issue_dma(0);
  loadA(0);

  for (int T = 0; T < 32; ++T) {
    __syncthreads();  // drains own DMA(T)+A(T) (vmcnt) ; barrier -> buf ready

    bf16x8 ah, al;
    split8(xq0, xq1, gq0, gq1, sx, sxx, ah, al);
    if (T + 1 < 32) loadA(T + 1);   // prefetch; latency hidden under MFMA

    __builtin_amdgcn_s_setprio(1);
#pragma unroll
    for (int nt = 0; nt < 13; ++nt) {
      bf16x8 bh = *(const bf16x8*)(rdB + nt * 1024);
      bf16x8 bl = *(const bf16x8*)(rdB + PLB + nt * 1024);
      acc[nt] = __builtin_amdgcn_mfma_f32_16x16x32_bf16(ah, bh, acc[nt], 0, 0, 0);
      acc[nt] = __builtin_amdgcn_mfma_f32_16x16x32_bf16(al, bh, acc[nt], 0, 0, 0);
      acc[nt] = __builtin_amdgcn_mfma_f32_16x16x32_bf16(ah, bl, acc[nt], 0, 0, 0);
    }
    __builtin_amdgcn_s_setprio(0);

    __syncthreads();  // all waves done reading buf -> safe to overwrite
    if (T + 1 < 32) issue_dma(T + 1);  // lands during other blocks' compute
  }

  // row stats: butterfly over quads -> every lane holds totals for its m
  sx += __shfl_xor(sx, 16, 64);  sxx += __shfl_xor(sxx, 16, 64);
  sx += __shfl_xor(sx, 32, 64);  sxx += __shfl_xor(sxx, 32, 64);
  float mean = sx * (1.0f / Hd);
  float rstd = rsqrtf(sxx * (1.0f / Hd) - mean * mean + EPSf);

  float Gc[13], Bc[13];
#pragma unroll
  for (int nt = 0; nt < 13; ++nt) {
    int col = b * NKP + nt * 16 + m;
    Gc[nt] = Gv[col];
    Bc[nt] = Bv[col];
  }

  // epilogue in 2 passes of 32 rows (z-buffer aliases the dead B buffer)
  // C layout: col = lane&15, row = quad*4 + reg. Wave w owns block rows
  // [w*16, w*16+16); pass 0 = waves 0,1 (rows 0..31), pass 1 = waves 2,3.
#pragma unroll
  for (int pass = 0; pass < 2; ++pass) {
    __syncthreads();  // B (or previous z pass) fully consumed
    if ((wave >> 1) == pass) {
      int zb = (wave & 1) * 16;
#pragma unroll
      for (int r = 0; r < 4; ++r) {
        int lr = quad * 4 + r;
        float mn = __shfl(mean, lr, 16), rs = __shfl(rstd, lr, 16);
        float mrs = mn * rs;
#pragma unroll
        for (int nt = 0; nt < 13; ++nt)
          sm.z[zb + lr][nt * 16 + m] = rs * acc[nt][r] - mrs * Gc[nt] + Bc[nt];
      }
    }
    __syncthreads();

    // phase 1: group maxes in-place (32 rows x 20 groups of 10)
    for (int i = t; i < ZR * Nd; i += 256) {
      int row = i / Nd, g = i - row * Nd;
      float* zp = &sm.z[row][g * Kd];
      float mx = zp[0];
#pragma unroll
      for (int j = 1; j < Kd; ++j) mx = fmaxf(mx, zp[j]);
      zp[0] = mx;
    }
    __syncthreads();

    // phase 2: min over N, concat, argmax (+top-2 gap flag), write
    if (t < ZR) {
      int row = t;
      float mn = 3.4e38f, v1 = -3.4e38f, v2 = -3.4e38f;
      int best = 0;
      size_t orow = qrow0 + pass * ZR + row;
      float* lp = out_logits + orow * (Nd + 1);
#pragma unroll
      for (int n = 0; n < Nd; ++n) {
        float v = sm.z[row][n * Kd];
        lp[n] = v;
        mn = fminf(mn, v);
        if (v > v1) { v2 = v1; v1 = v; best = n; }  // first-occurrence argmax
        else v2 = fmaxf(v2, v);
      }
      lp[Nd] = mn - 1.0f;  // strictly below min, never the argmax
      out_pred[orow] = (float)best;
      if (v1 - v2 < TAU) {
        int idx = atomicAdd(flag_cnt, 1);
        if (idx < MAXF) flag_list[idx] = (int)orow;
      }
    }
  }
}

// ---------------- fp64 exact refinement for near-tie rows ----------------
__global__ __launch_bounds__(256) void refine_pred(
    const float* __restrict__ query, const float* __restrict__ support,
    const float* __restrict__ gamma, const float* __restrict__ beta,
    const int* __restrict__ flag_cnt, const int* __restrict__ flag_list,
    float* __restrict__ out_pred) {
  __shared__ double A[Hd];     // qn_full * gamma
  __shared__ double red[16];
  __shared__ double zbuf[NKd];
  __shared__ double gmax[Nd];
  int cnt = *flag_cnt; if (cnt > MAXF) cnt = MAXF;
  if ((int)blockIdx.x >= cnt) return;
  int qrow = flag_list[blockIdx.x];
  int b = qrow / Qd;
  int t = threadIdx.x, lane = t & 63, w = t >> 6;
  const float* qx = query + (size_t)qrow * Hd;
  float xv[4];
  double sx = 0.0, sxx = 0.0;
#pragma unroll
  for (int i = 0; i < 4; ++i) {
    xv[i] = qx[t * 4 + i];
    sx += (double)xv[i]; sxx += (double)xv[i] * (double)xv[i];
  }
#pragma unroll
  for (int o = 32; o; o >>= 1) { sx += __shfl_xor(sx, o, 64); sxx += __shfl_xor(sxx, o, 64); }
  if (lane == 0) { red[w] = sx; red[8 + w] = sxx; }
  __syncthreads();
  double m = (red[0] + red[1] + red[2] + red[3]) * (1.0 / Hd);
  double var = (red[8] + red[9] + red[10] + red[11]) * (1.0 / Hd) - m * m;
  double r = 1.0 / sqrt(var + 1e-5);
  double s1 = 0.0, s2 = 0.0;
#pragma unroll
  for (int i = 0; i < 4; ++i) {
    int j = t * 4 + i;
    double g = (double)gamma[j], be = (double)beta[j];
    double qn = ((double)xv[i] - m) * r * g + be;
    double a = qn * g;
    A[j] = a; s1 += a; s2 += qn * be;
  }
#pragma unroll
  for (int o = 32; o; o >>= 1) { s1 += __shfl_xor(s1, o, 64); s2 += __shfl_xor(s2, o, 64); }
  __syncthreads();
  if (lane == 0) { red[w] = s1; red[8 + w] = s2; }
  __syncthreads();
  double S1 = red[0] + red[1] + red[2] + red[3];
  double S2 = red[8] + red[9] + red[10] + red[11];
  const float* sbase = support + (size_t)b * NKd * Hd;
  for (int row = w; row < NKd; row += 4) {
    const float* xr = sbase + (size_t)row * Hd;
    double tx = 0.0, txx = 0.0, tax = 0.0;
#pragma unroll
    for (int i = 0; i < 16; ++i) {
      int j = lane + i * 64;
      double x = (double)xr[j];
      tx += x; txx += x * x; tax += A[j] * x;
    }
#pragma unroll
    for (int o = 32; o; o >>= 1) {
      tx += __shfl_xor(tx, o, 64); txx += __shfl_xor(txx, o, 64); tax += __shfl_xor(tax, o, 64);
    }
    if (lane == 0) {
      double mm = tx * (1.0 / Hd);
      double vv = txx * (1.0 / Hd) - mm * mm;
      double rr = 1.0 / sqrt(vv + 1e-5);
      zbuf[row] = rr * (tax - mm * S1) + S2;
    }
  }
  __syncthreads();
  if (t < Nd) {
    double mx = zbuf[t * Kd];
#pragma unroll
    for (int j = 1; j < Kd; ++j) mx = fmax(mx, zbuf[t * Kd + j]);
    gmax[t] = mx;
  }
  __syncthreads();
  if (t == 0) {
    double bv = gmax[0]; int best = 0;
#pragma unroll
    for (int n = 1; n < Nd; ++n) if (gmax[n] > bv) { bv = gmax[n]; best = n; }
    out_pred[qrow] = (float)best;
  }
}

extern "C" void kernel_launch(void* const* d_in, const int* in_sizes, int n_in,
                              void* d_out, int out_size, void* d_ws, size_t ws_size,
                              hipStream_t stream) {
  const float* support = (const float*)d_in[0];
  const float* query   = (const float*)d_in[1];
  const float* gamma   = (const float*)d_in[2];
  const float* beta    = (const float*)d_in[3];

  float* out = (float*)d_out;
  float* out_logits = out;                                  // 32*2048*21
  float* out_pred   = out + (size_t)Bd * Qd * (Nd + 1);     // 32*2048

  const size_t plane = (size_t)Bd * 32 * TCH;               // == Bd*NKP*Hd elems
  unsigned short* s_hi = (unsigned short*)d_ws;             // 13.6 MB
  unsigned short* s_lo = s_hi + plane;                      // 13.6 MB
  char* p = (char*)(s_lo + plane);
  float* Gv = (float*)p;            p += (size_t)Bd * NKP * sizeof(float);
  float* Bv = (float*)p;            p += (size_t)Bd * NKP * sizeof(float);
  int* flag_cnt = (int*)p;
  int* flag_list = (int*)(p + 256);

  hipMemsetAsync(flag_cnt, 0, sizeof(int), stream);
  ln_support<<<(Bd * NKP) / 4, 256, 0, stream>>>(support, gamma, beta, s_hi, s_lo, Gv, Bv);
  gemm_reduce<<<Qd / BM * Bd, 256, 0, stream>>>(query, s_hi, s_lo, gamma, Gv, Bv,
                                                out_logits, out_pred, flag_cnt, flag_list);
  refine_pred<<<MAXF, 256, 0, stream>>>(query, support, gamma, beta, flag_cnt, flag_list, out_pred);
}

// Round 4
// 484.780 us; speedup vs baseline: 1.0311x; 1.0124x over previous
//
#include <hip/hip_runtime.h>
#include <hip/hip_bf16.h>

// Problem constants (fixed by the reference)
#define Hd   1024
#define Bd   32
#define Nd   20
#define Kd   10
#define NKd  200   // N*K support rows per batch
#define NKP  208   // padded to 13 * 16
#define Qd   2048
#define BM   128   // query rows per block (4 waves x 32 rows each)
#define ZR   64    // z-buffer rows per epilogue pass (two passes)
#define ZLD  209   // z-buffer LDS row stride
#define EPSf 1e-5f
#define TAU  0.02f // top-2 gap below which we refine in fp64
#define MAXF 2048
#define TCH  (832 * 8)   // ushorts per (batch,tile,plane) block
#define PLB  (TCH * 2)   // plane stride in bytes  (13312)
#define BUFB (2 * PLB)   // buffer stride in bytes (26624)

typedef __attribute__((ext_vector_type(8))) short bf16x8;
typedef __attribute__((ext_vector_type(4))) float f32x4;
typedef __attribute__((ext_vector_type(4))) unsigned int u32x4;

// chunk swizzle: slot = k8 ^ SWS(row). SWS(r) changes under r->r+4/+8/+12, so
// every consecutive-8-lane phase of a ds_read_b128 hits 8 distinct 16B slots.
#define SWS(r) (((r) ^ ((r) >> 2)) & 3)

static __device__ __forceinline__ unsigned short f2bf(float f) {
  union { float f; unsigned u; } c; c.f = f;
  unsigned r = c.u + 0x7FFFu + ((c.u >> 16) & 1u);  // RNE
  return (unsigned short)(r >> 16);
}
static __device__ __forceinline__ float bf2f(unsigned short h) {
  union { unsigned u; float f; } c; c.u = ((unsigned)h) << 16;
  return c.f;
}
static __device__ __forceinline__ float ubitf(unsigned u) {
  union { unsigned u; float f; } c; c.u = u; return c.f;
}
static __device__ __forceinline__ unsigned cvtpk_bf16(float a, float b) {
  unsigned r;  // dst.lo16 = bf16(a), dst.hi16 = bf16(b)
  asm("v_cvt_pk_bf16_f32 %0, %1, %2" : "=v"(r) : "v"(a), "v"(b));
  return r;
}
static __device__ __forceinline__ void gload_lds16(const void* g, void* l) {
  __builtin_amdgcn_global_load_lds(
      (const __attribute__((address_space(1))) unsigned int*)g,
      (__attribute__((address_space(3))) unsigned int*)l, 16, 0, 0);
}

// ---- LayerNorm support -> split bf16 (hi, lo) planes in tile-major, pre-swizzled
//      layout: plane[((b*32 + T)*832 + row*4 + (k8 ^ SWS(row))) * 8 ..+8].
//      Also per-row scalars G = sum(gamma*sn), Bt = sum(beta*sn). One wave/row.
__global__ __launch_bounds__(256) void ln_support(const float* __restrict__ x,
                                                  const float* __restrict__ gamma,
                                                  const float* __restrict__ beta,
                                                  unsigned short* __restrict__ y_hi,
                                                  unsigned short* __restrict__ y_lo,
                                                  float* __restrict__ Gv,
                                                  float* __restrict__ Bv) {
  int wave = threadIdx.x >> 6, lane = threadIdx.x & 63;
  int p = blockIdx.x * 4 + wave;          // padded row id in [0, Bd*NKP)
  int b = p / NKP, rr = p - b * NKP;
  int T0 = lane >> 1;                     // this lane's K-tile (2 lanes per tile)
  int k8base = (lane & 1) * 2;            // first of this lane's 2 chunks in the tile
  int sw = SWS(rr);
  size_t chunkbase = (size_t)b * 32 * TCH + (size_t)T0 * TCH + (size_t)rr * 32;

  if (rr >= NKd) {                        // padding row: zero-fill
    bf16x8 z8 = {0, 0, 0, 0, 0, 0, 0, 0};
#pragma unroll
    for (int pr = 0; pr < 2; ++pr) {
      size_t off = chunkbase + (size_t)(((k8base + pr) ^ sw) * 8);
      *(bf16x8*)(y_hi + off) = z8;
      *(bf16x8*)(y_lo + off) = z8;
    }
    if (lane == 0) { Gv[p] = 0.f; Bv[p] = 0.f; }
    return;
  }
  // lane handles cols [lane*16, lane*16+16)
  const float4* xr = (const float4*)(x + ((size_t)b * NKd + rr) * Hd);
  const float4* gr = (const float4*)gamma;
  const float4* br = (const float4*)beta;
  float4 v[4];
  float s = 0.f, ss = 0.f;
#pragma unroll
  for (int j = 0; j < 4; ++j) {
    v[j] = xr[lane * 4 + j];
    s  += v[j].x + v[j].y + v[j].z + v[j].w;
    ss += v[j].x * v[j].x + v[j].y * v[j].y + v[j].z * v[j].z + v[j].w * v[j].w;
  }
#pragma unroll
  for (int o = 32; o; o >>= 1) { s += __shfl_xor(s, o, 64); ss += __shfl_xor(ss, o, 64); }
  float mean = s * (1.0f / Hd);
  float rstd = rsqrtf(ss * (1.0f / Hd) - mean * mean + EPSf);

  float nx[16];
  float sg = 0.f, sb = 0.f;
#pragma unroll
  for (int j = 0; j < 4; ++j) {
    float4 g = gr[lane * 4 + j], bb = br[lane * 4 + j];
    float xv[4] = {v[j].x, v[j].y, v[j].z, v[j].w};
    float gv4[4] = {g.x, g.y, g.z, g.w};
    float bv4[4] = {bb.x, bb.y, bb.z, bb.w};
#pragma unroll
    for (int e = 0; e < 4; ++e) {
      float n = (xv[e] - mean) * rstd * gv4[e] + bv4[e];
      nx[j * 4 + e] = n;
      sg += n * gv4[e];
      sb += n * bv4[e];
    }
  }
#pragma unroll
  for (int pr = 0; pr < 2; ++pr) {
    bf16x8 ph, pl;
#pragma unroll
    for (int e = 0; e < 8; ++e) {
      float n = nx[pr * 8 + e];
      unsigned short h = f2bf(n);
      ph[e] = (short)h;
      pl[e] = (short)f2bf(n - bf2f(h));
    }
    size_t off = chunkbase + (size_t)(((k8base + pr) ^ sw) * 8);
    *(bf16x8*)(y_hi + off) = ph;
    *(bf16x8*)(y_lo + off) = pl;
  }
#pragma unroll
  for (int o = 32; o; o >>= 1) { sg += __shfl_xor(sg, o, 64); sb += __shfl_xor(sb, o, 64); }
  if (lane == 0) { Gv[p] = sg; Bv[p] = sb; }
}

// split x*gamma into bf16 hi/lo planes (packed via v_cvt_pk_bf16_f32) and
// accumulate raw-x stats. hi rounding mode is irrelevant (lo catches residual).
static __device__ __forceinline__ void split8(float4 xa, float4 xb, float4 ga, float4 gb,
                                              float& sx, float& sxx,
                                              bf16x8& AH, bf16x8& AL) {
  float x[8] = {xa.x, xa.y, xa.z, xa.w, xb.x, xb.y, xb.z, xb.w};
  float g[8] = {ga.x, ga.y, ga.z, ga.w, gb.x, gb.y, gb.z, gb.w};
  float u[8];
#pragma unroll
  for (int e = 0; e < 8; ++e) {
    sx += x[e];
    sxx = fmaf(x[e], x[e], sxx);
    u[e] = x[e] * g[e];
  }
  unsigned h[4], l[4];
#pragma unroll
  for (int p = 0; p < 4; ++p) {
    h[p] = cvtpk_bf16(u[2 * p], u[2 * p + 1]);
    float r0 = ubitf(h[p] << 16);
    float r1 = ubitf(h[p] & 0xFFFF0000u);
    l[p] = cvtpk_bf16(u[2 * p] - r0, u[2 * p + 1] - r1);
  }
  AH = __builtin_bit_cast(bf16x8, (u32x4){h[0], h[1], h[2], h[3]});
  AL = __builtin_bit_cast(bf16x8, (u32x4){l[0], l[1], l[2], l[3]});
}

#define MFMA_BF16 __builtin_amdgcn_mfma_f32_16x16x32_bf16

// ---- fused GEMM + stats + group-max/min/argmax.
// Each wave owns M=32 query rows (2 A-fragments). B double-buffered via
// global_load_lds. Each K-tile is split into 4 fine-grained phases
// {ds_read nt-group || issue DMA share || (p0: A-prefetch)} -> s_barrier ->
// setprio(1) MFMA-group setprio(0). The raw barriers are pure rendezvous
// (no vmcnt) that stagger load-issue vs MFMA roles across waves (T3 fine
// interleave; R2's coarse variant was the m196 anti-pattern). Tile-top
// __syncthreads provides the only RAW-hazard drain (all in-flight ops are
// >=1 phase old there, so the drain is cheap).
// z[q][s] = rstd_q * D - mean_q * rstd_q * G[s] + Bt[s],  D = (x .* gamma) . sn
__global__ __launch_bounds__(256, 2) void gemm_reduce(
    const float* __restrict__ query,
    const unsigned short* __restrict__ s_hi, const unsigned short* __restrict__ s_lo,
    const float* __restrict__ gamma,
    const float* __restrict__ Gv, const float* __restrict__ Bv,
    float* __restrict__ out_logits, float* __restrict__ out_pred,
    int* __restrict__ flag_cnt, int* __restrict__ flag_list) {
  __shared__ __align__(16) union {
    unsigned short B[2][2][TCH];   // [buf][plane]: 53248 B
    float z[ZR][ZLD];              // 53504 B (one 64-row pass at a time)
  } sm;

  // XCD-locality decode: all 16 m-tiles of a batch land on one XCD (lin % 8)
  int lin = blockIdx.x;
  int xcd = lin & 7, sl = lin >> 3;
  int b = xcd + 8 * (sl >> 4);
  int m0 = (sl & 15) * BM;
  int t = threadIdx.x;
  int wave = t >> 6, lane = t & 63;
  int m = lane & 15, quad = lane >> 4;

  const size_t qrow0 = (size_t)b * Qd + m0;
  const float* qf0 = query + (qrow0 + wave * 32 + m) * Hd;   // fragment 0 row
  const float* qf1 = qf0 + 16 * Hd;                          // fragment 1 row
  const unsigned short* hb = s_hi + (size_t)b * 32 * TCH;
  const unsigned short* lb = s_lo + (size_t)b * 32 * TCH;

  char* ldsB = (char*)&sm.B[0][0][0];
  // read slot depends only on m (row = nt*16+m) -> one base VGPR; all 26
  // reads/T are base + compile-time offset (max 53232 < 64K).
  const char* rdB = ldsB + m * 64 + ((quad ^ SWS(m)) * 16);

  // wave's 7 DMA instrs (block-wide 26) spread across the 4 phases:
  // phase p issues this wave's chunks i = p, p+4 (i < 7).
  auto issue_dma_phase = [&](int Tn, int bufsel, int p) {
    size_t toff = (size_t)Tn * TCH;
    char* dstb = ldsB + bufsel * BUFB;
#pragma unroll
    for (int i = p; i < 7; i += 4) {
      int j = wave + i * 4;
      if (j < 26) {
        int pl = j >= 13 ? 1 : 0, jj = j - pl * 13;
        const unsigned short* src = (pl ? lb : hb) + toff + (size_t)jj * 512 + lane * 8;
        gload_lds16(src, dstb + pl * PLB + jj * 1024);
      }
    }
  };

  float4 xq00, xq01, xq10, xq11, gq0, gq1;
  auto loadA = [&](int T) {
    int ko = T * 32 + quad * 8;
    const float4* g4 = (const float4*)(gamma + ko);
    gq0 = g4[0]; gq1 = g4[1];
    const float4* q0 = (const float4*)(qf0 + ko);
    xq00 = q0[0]; xq01 = q0[1];
    const float4* q1 = (const float4*)(qf1 + ko);
    xq10 = q1[0]; xq11 = q1[1];
  };

  f32x4 acc0[13], acc1[13];
#pragma unroll
  for (int i = 0; i < 13; ++i) {
    acc0[i] = (f32x4){0.f, 0.f, 0.f, 0.f};
    acc1[i] = (f32x4){0.f, 0.f, 0.f, 0.f};
  }
  float sx0 = 0.f, sxx0 = 0.f, sx1 = 0.f, sxx1 = 0.f;

  // prologue: DMA tile 0 -> buf 0; prefetch A(0) into registers
#pragma unroll
  for (int p = 0; p < 4; ++p) issue_dma_phase(0, 0, p);
  loadA(0);

  for (int T = 0; T < 32; ++T) {
    int u = T & 1;
    __syncthreads();  // tile-top drain: DMA(T)+A(T) are >=1 MFMA-phase old

    bf16x8 ah0, al0, ah1, al1;
    split8(xq00, xq01, gq0, gq1, sx0, sxx0, ah0, al0);
    split8(xq10, xq11, gq0, gq1, sx1, sxx1, ah1, al1);

    const char* Bu = rdB + (u ? BUFB : 0);

    // ---- phase 0: nt 0..3 (12 MFMA), + A(T+1) prefetch
    {
      bf16x8 bh[4], bl[4];
#pragma unroll
      for (int i = 0; i < 4; ++i) {
        bh[i] = *(const bf16x8*)(Bu + i * 1024);
        bl[i] = *(const bf16x8*)(Bu + PLB + i * 1024);
      }
      if (T + 1 < 32) { issue_dma_phase(T + 1, 1 - u, 0); loadA(T + 1); }
      __builtin_amdgcn_s_barrier();
      __builtin_amdgcn_sched_barrier(0);
      __builtin_amdgcn_s_setprio(1);
#pragma unroll
      for (int i = 0; i < 4; ++i) {
        acc0[i] = MFMA_BF16(ah0, bh[i], acc0[i], 0, 0, 0);
        acc1[i] = MFMA_BF16(ah1, bh[i], acc1[i], 0, 0, 0);
        acc0[i] = MFMA_BF16(al0, bh[i], acc0[i], 0, 0, 0);
        acc1[i] = MFMA_BF16(al1, bh[i], acc1[i], 0, 0, 0);
        acc0[i] = MFMA_BF16(ah0, bl[i], acc0[i], 0, 0, 0);
        acc1[i] = MFMA_BF16(ah1, bl[i], acc1[i], 0, 0, 0);
      }
      __builtin_amdgcn_s_setprio(0);
    }
    // ---- phases 1..3: nt groups {4-6},{7-9},{10-12} (9 MFMA each)
#pragma unroll
    for (int p = 1; p < 4; ++p) {
      int base = 1 + p * 3;
      bf16x8 bh[3], bl[3];
#pragma unroll
      for (int i = 0; i < 3; ++i) {
        bh[i] = *(const bf16x8*)(Bu + (base + i) * 1024);
        bl[i] = *(const bf16x8*)(Bu + PLB + (base + i) * 1024);
      }
      if (T + 1 < 32) issue_dma_phase(T + 1, 1 - u, p);
      __builtin_amdgcn_s_barrier();
      __builtin_amdgcn_sched_barrier(0);
      __builtin_amdgcn_s_setprio(1);
#pragma unroll
      for (int i = 0; i < 3; ++i) {
        int nt = base + i;
        acc0[nt] = MFMA_BF16(ah0, bh[i], acc0[nt], 0, 0, 0);
        acc1[nt] = MFMA_BF16(ah1, bh[i], acc1[nt], 0, 0, 0);
        acc0[nt] = MFMA_BF16(al0, bh[i], acc0[nt], 0, 0, 0);
        acc1[nt] = MFMA_BF16(al1, bh[i], acc1[nt], 0, 0, 0);
        acc0[nt] = MFMA_BF16(ah0, bl[i], acc0[nt], 0, 0, 0);
        acc1[nt] = MFMA_BF16(ah1, bl[i], acc1[nt], 0, 0, 0);
      }
      __builtin_amdgcn_s_setprio(0);
    }
  }

  // row stats: butterfly over quads -> every lane holds totals for its m
  sx0 += __shfl_xor(sx0, 16, 64);  sxx0 += __shfl_xor(sxx0, 16, 64);
  sx0 += __shfl_xor(sx0, 32, 64);  sxx0 += __shfl_xor(sxx0, 32, 64);
  sx1 += __shfl_xor(sx1, 16, 64);  sxx1 += __shfl_xor(sxx1, 16, 64);
  sx1 += __shfl_xor(sx1, 32, 64);  sxx1 += __shfl_xor(sxx1, 32, 64);
  float mean0 = sx0 * (1.0f / Hd);
  float rstd0 = rsqrtf(sxx0 * (1.0f / Hd) - mean0 * mean0 + EPSf);
  float mean1 = sx1 * (1.0f / Hd);
  float rstd1 = rsqrtf(sxx1 * (1.0f / Hd) - mean1 * mean1 + EPSf);

  float Gc[13], Bc[13];
#pragma unroll
  for (int nt = 0; nt < 13; ++nt) {
    int col = b * NKP + nt * 16 + m;
    Gc[nt] = Gv[col];
    Bc[nt] = Bv[col];
  }

  // epilogue in 2 passes of 64 rows (z-buffer aliases the dead B buffers)
  // C layout: col = lane&15, row = quad*4 + reg
#pragma unroll
  for (int pass = 0; pass < 2; ++pass) {
    __syncthreads();  // B (or previous z pass) fully consumed
    if ((wave >> 1) == pass) {
      int zb = (wave & 1) * 32;
#pragma unroll
      for (int r = 0; r < 4; ++r) {
        int lr = quad * 4 + r;
        {
          float mn = __shfl(mean0, lr, 16), rs = __shfl(rstd0, lr, 16);
          float mrs = mn * rs;
#pragma unroll
          for (int nt = 0; nt < 13; ++nt)
            sm.z[zb + lr][nt * 16 + m] = rs * acc0[nt][r] - mrs * Gc[nt] + Bc[nt];
        }
        {
          float mn = __shfl(mean1, lr, 16), rs = __shfl(rstd1, lr, 16);
          float mrs = mn * rs;
#pragma unroll
          for (int nt = 0; nt < 13; ++nt)
            sm.z[zb + 16 + lr][nt * 16 + m] = rs * acc1[nt][r] - mrs * Gc[nt] + Bc[nt];
        }
      }
    }
    __syncthreads();

    // phase 1: group maxes in-place (64 rows x 20 groups of 10)
    for (int i = t; i < ZR * Nd; i += 256) {
      int row = i / Nd, g = i - row * Nd;
      float* zp = &sm.z[row][g * Kd];
      float mx = zp[0];
#pragma unroll
      for (int j = 1; j < Kd; ++j) mx = fmaxf(mx, zp[j]);
      zp[0] = mx;
    }
    __syncthreads();

    // phase 2: min over N, concat, argmax (+top-2 gap flag), write
    if (t < ZR) {
      int row = t;
      float mn = 3.4e38f, v1 = -3.4e38f, v2 = -3.4e38f;
      int best = 0;
      size_t orow = qrow0 + pass * ZR + row;
      float* lp = out_logits + orow * (Nd + 1);
#pragma unroll
      for (int n = 0; n < Nd; ++n) {
        float v = sm.z[row][n * Kd];
        lp[n] = v;
        mn = fminf(mn, v);
        if (v > v1) { v2 = v1; v1 = v; best = n; }  // first-occurrence argmax
        else v2 = fmaxf(v2, v);
      }
      lp[Nd] = mn - 1.0f;  // strictly below min, never the argmax
      out_pred[orow] = (float)best;
      if (v1 - v2 < TAU) {
        int idx = atomicAdd(flag_cnt, 1);
        if (idx < MAXF) flag_list[idx] = (int)orow;
      }
    }
  }
}

// ---------------- fp64 exact refinement for near-tie rows ----------------
__global__ __launch_bounds__(256) void refine_pred(
    const float* __restrict__ query, const float* __restrict__ support,
    const float* __restrict__ gamma, const float* __restrict__ beta,
    const int* __restrict__ flag_cnt, const int* __restrict__ flag_list,
    float* __restrict__ out_pred) {
  __shared__ double A[Hd];     // qn_full * gamma
  __shared__ double red[16];
  __shared__ double zbuf[NKd];
  __shared__ double gmax[Nd];
  int cnt = *flag_cnt; if (cnt > MAXF) cnt = MAXF;
  if ((int)blockIdx.x >= cnt) return;
  int qrow = flag_list[blockIdx.x];
  int b = qrow / Qd;
  int t = threadIdx.x, lane = t & 63, w = t >> 6;
  const float* qx = query + (size_t)qrow * Hd;
  float xv[4];
  double sx = 0.0, sxx = 0.0;
#pragma unroll
  for (int i = 0; i < 4; ++i) {
    xv[i] = qx[t * 4 + i];
    sx += (double)xv[i]; sxx += (double)xv[i] * (double)xv[i];
  }
#pragma unroll
  for (int o = 32; o; o >>= 1) { sx += __shfl_xor(sx, o, 64); sxx += __shfl_xor(sxx, o, 64); }
  if (lane == 0) { red[w] = sx; red[8 + w] = sxx; }
  __syncthreads();
  double m = (red[0] + red[1] + red[2] + red[3]) * (1.0 / Hd);
  double var = (red[8] + red[9] + red[10] + red[11]) * (1.0 / Hd) - m * m;
  double r = 1.0 / sqrt(var + 1e-5);
  double s1 = 0.0, s2 = 0.0;
#pragma unroll
  for (int i = 0; i < 4; ++i) {
    int j = t * 4 + i;
    double g = (double)gamma[j], be = (double)beta[j];
    double qn = ((double)xv[i] - m) * r * g + be;
    double a = qn * g;
    A[j] = a; s1 += a; s2 += qn * be;
  }
#pragma unroll
  for (int o = 32; o; o >>= 1) { s1 += __shfl_xor(s1, o, 64); s2 += __shfl_xor(s2, o, 64); }
  __syncthreads();
  if (lane == 0) { red[w] = s1; red[8 + w] = s2; }
  __syncthreads();
  double S1 = red[0] + red[1] + red[2] + red[3];
  double S2 = red[8] + red[9] + red[10] + red[11];
  const float* sbase = support + (size_t)b * NKd * Hd;
  for (int row = w; row < NKd; row += 4) {
    const float* xr = sbase + (size_t)row * Hd;
    double tx = 0.0, txx = 0.0, tax = 0.0;
#pragma unroll
    for (int i = 0; i < 16; ++i) {
      int j = lane + i * 64;
      double x = (double)xr[j];
      tx += x; txx += x * x; tax += A[j] * x;
    }
#pragma unroll
    for (int o = 32; o; o >>= 1) {
      tx += __shfl_xor(tx, o, 64); txx += __shfl_xor(txx, o, 64); tax += __shfl_xor(tax, o, 64);
    }
    if (lane == 0) {
      double mm = tx * (1.0 / Hd);
      double vv = txx * (1.0 / Hd) - mm * mm;
      double rr = 1.0 / sqrt(vv + 1e-5);
      zbuf[row] = rr * (tax - mm * S1) + S2;
    }
  }
  __syncthreads();
  if (t < Nd) {
    double mx = zbuf[t * Kd];
#pragma unroll
    for (int j = 1; j < Kd; ++j) mx = fmax(mx, zbuf[t * Kd + j]);
    gmax[t] = mx;
  }
  __syncthreads();
  if (t == 0) {
    double bv = gmax[0]; int best = 0;
#pragma unroll
    for (int n = 1; n < Nd; ++n) if (gmax[n] > bv) { bv = gmax[n]; best = n; }
    out_pred[qrow] = (float)best;
  }
}

extern "C" void kernel_launch(void* const* d_in, const int* in_sizes, int n_in,
                              void* d_out, int out_size, void* d_ws, size_t ws_size,
                              hipStream_t stream) {
  const float* support = (const float*)d_in[0];
  const float* query   = (const float*)d_in[1];
  const float* gamma   = (const float*)d_in[2];
  const float* beta    = (const float*)d_in[3];

  float* out = (float*)d_out;
  float* out_logits = out;                                  // 32*2048*21
  float* out_pred   = out + (size_t)Bd * Qd * (Nd + 1);     // 32*2048

  const size_t plane = (size_t)Bd * 32 * TCH;               // == Bd*NKP*Hd elems
  unsigned short* s_hi = (unsigned short*)d_ws;             // 13.6 MB
  unsigned short* s_lo = s_hi + plane;                      // 13.6 MB
  char* p = (char*)(s_lo + plane);
  float* Gv = (float*)p;            p += (size_t)Bd * NKP * sizeof(float);
  float* Bv = (float*)p;            p += (size_t)Bd * NKP * sizeof(float);
  int* flag_cnt = (int*)p;
  int* flag_list = (int*)(p + 256);

  hipMemsetAsync(flag_cnt, 0, sizeof(int), stream);
  ln_support<<<(Bd * NKP) / 4, 256, 0, stream>>>(support, gamma, beta, s_hi, s_lo, Gv, Bv);
  gemm_reduce<<<Qd / BM * Bd, 256, 0, stream>>>(query, s_hi, s_lo, gamma, Gv, Bv,
                                                out_logits, out_pred, flag_cnt, flag_list);
  refine_pred<<<MAXF, 256, 0, stream>>>(query, support, gamma, beta, flag_cnt, flag_list, out_pred);
}